// Round 3
// baseline (364.417 us; speedup 1.0000x reference)
//
#include <hip/hip_runtime.h>

#define HEADS 4
#define OUTC 64
#define INC 128
#define HC 256   // HEADS*OUTC
#define NEG 0.2f

typedef __attribute__((ext_vector_type(8))) short bf16x8;
typedef __attribute__((ext_vector_type(4))) float f32x4;

static __device__ __forceinline__ float bf2f(unsigned short u){
  unsigned int x = ((unsigned int)u) << 16;
  return __uint_as_float(x);
}
static __device__ __forceinline__ float bflo(unsigned int u){
  return __uint_as_float(u << 16);
}
static __device__ __forceinline__ float bfhi(unsigned int u){
  return __uint_as_float(u & 0xffff0000u);
}
static __device__ __forceinline__ unsigned short f2bf(float f){
  unsigned int x = __float_as_uint(f);
  unsigned int lsb = (x >> 16) & 1u;
  x += 0x7fffu + lsb;           // RNE
  return (unsigned short)(x >> 16);
}
static __device__ __forceinline__ void split8(float4 a, float4 b, bf16x8& hi, bf16x8& lo){
  float v[8] = {a.x, a.y, a.z, a.w, b.x, b.y, b.z, b.w};
  #pragma unroll
  for (int i = 0; i < 8; ++i){
    unsigned short h = f2bf(v[i]);
    hi[i] = (short)h;
    lo[i] = (short)f2bf(v[i] - bf2f(h));
  }
}

// ---- edge canonicalize (per-wave int64/int32 detection) + degree histogram ----
__global__ void k_conv_e_hist(const int* __restrict__ ei,
                              int* __restrict__ srcc, int* __restrict__ dstc,
                              int* __restrict__ pos, int* __restrict__ deg, int E){
  int e = blockIdx.x * 256 + threadIdx.x;
  bool valid = (e < E);
  int ee = valid ? e : 0;
  int hiw = ei[2 * ee + 1];
  bool hz = valid ? (hiw == 0) : true;
  unsigned long long mask = __ballot(hz);
  bool i64 = (mask == ~0ULL);
  int s, d;
  if (i64){ s = ei[2 * ee]; d = ei[2 * (size_t)E + 2 * ee]; }
  else    { s = ei[ee];     d = ei[(size_t)E + ee]; }
  if (valid){
    srcc[e] = s; dstc[e] = d;
    pos[e] = atomicAdd(&deg[d], 1);
  }
}

// ---- split + transpose W into bf16 hi/lo ----
__global__ void k_split_w(const float* __restrict__ W, unsigned short* __restrict__ Wthi,
                          unsigned short* __restrict__ Wtlo){
  int t = blockIdx.x * 256 + threadIdx.x;        // 0..32767
  int k = t >> 8, n = t & 255;
  float v = W[t];
  unsigned short hi = f2bf(v);
  Wthi[n * INC + k] = hi;
  Wtlo[n * INC + k] = f2bf(v - bf2f(hi));
}

// ---- fused GEMM + attention logits (round-0 decomposition, head-major XPh store) ----
// block = 64 rows x 256 cols; wave w = head w: 4 row-tiles x 4 col-tiles of 16x16.
__global__ __launch_bounds__(256) void k_gemm_fused(const float* __restrict__ X,
    const unsigned short* __restrict__ Wthi, const unsigned short* __restrict__ Wtlo,
    const float* __restrict__ att_src, const float* __restrict__ att_dst,
    unsigned short* __restrict__ XPh /*[H][N][64]*/, float* __restrict__ a_src,
    float* __restrict__ a_dst, int N){
  int w = threadIdx.x >> 6, lane = threadIdx.x & 63;
  int m0 = blockIdx.x * 64;
  int quad = lane >> 4;
  int l15 = lane & 15;
  int colg[4];
  #pragma unroll
  for (int t = 0; t < 4; ++t) colg[t] = w * 64 + t * 16 + l15;

  bool rv[4]; int rowr[4];
  #pragma unroll
  for (int rt = 0; rt < 4; ++rt){
    rv[rt] = (m0 + rt * 16) < N;                 // N%16==0 -> tile all-valid or all-out
    rowr[rt] = rv[rt] ? (m0 + rt * 16 + l15) : 0;
  }

  f32x4 acc[4][4];                               // [rt][t]
  #pragma unroll
  for (int rt = 0; rt < 4; ++rt)
    #pragma unroll
    for (int t = 0; t < 4; ++t) acc[rt][t] = (f32x4){0.f, 0.f, 0.f, 0.f};

  #pragma unroll
  for (int kk = 0; kk < 4; ++kk){
    // batch-issue all independent loads for this k-step
    float4 va[4], vb[4];
    #pragma unroll
    for (int rt = 0; rt < 4; ++rt){
      const float* xr = X + (size_t)rowr[rt] * INC + kk * 32 + quad * 8;
      va[rt] = *(const float4*)xr;
      vb[rt] = *(const float4*)(xr + 4);
    }
    bf16x8 bh[4], bl[4];
    #pragma unroll
    for (int t = 0; t < 4; ++t){
      size_t bo = (size_t)colg[t] * INC + kk * 32 + quad * 8;
      bh[t] = *(const bf16x8*)(Wthi + bo);
      bl[t] = *(const bf16x8*)(Wtlo + bo);
    }
    bf16x8 ah[4], al[4];
    #pragma unroll
    for (int rt = 0; rt < 4; ++rt) split8(va[rt], vb[rt], ah[rt], al[rt]);
    #pragma unroll
    for (int rt = 0; rt < 4; ++rt){
      #pragma unroll
      for (int t = 0; t < 4; ++t){
        acc[rt][t] = __builtin_amdgcn_mfma_f32_16x16x32_bf16(ah[rt], bh[t], acc[rt][t], 0, 0, 0);
        acc[rt][t] = __builtin_amdgcn_mfma_f32_16x16x32_bf16(ah[rt], bl[t], acc[rt][t], 0, 0, 0);
        acc[rt][t] = __builtin_amdgcn_mfma_f32_16x16x32_bf16(al[rt], bh[t], acc[rt][t], 0, 0, 0);
      }
    }
  }

  // store XPh (bf16), HEAD-MAJOR: head = w, local col = t*16+l15.
  // C/D layout: col=l15, row=quad*4+r
  #pragma unroll
  for (int rt = 0; rt < 4; ++rt){
    if (!rv[rt]) continue;
    #pragma unroll
    for (int t = 0; t < 4; ++t){
      #pragma unroll
      for (int r = 0; r < 4; ++r){
        XPh[((size_t)w * N + (m0 + rt * 16 + quad * 4 + r)) * OUTC + t * 16 + l15]
          = f2bf(acc[rt][t][r]);
      }
    }
  }

  // epilogue: head-w logits for the 64 rows
  float as[4], ad[4];
  #pragma unroll
  for (int t = 0; t < 4; ++t){
    as[t] = att_src[colg[t]];
    ad[t] = att_dst[colg[t]];
  }
  #pragma unroll
  for (int rt = 0; rt < 4; ++rt){
    if (!rv[rt]) continue;
    float ps[4], pd[4];
    #pragma unroll
    for (int r = 0; r < 4; ++r){
      ps[r] = acc[rt][0][r] * as[0] + acc[rt][1][r] * as[1]
            + acc[rt][2][r] * as[2] + acc[rt][3][r] * as[3];
      pd[r] = acc[rt][0][r] * ad[0] + acc[rt][1][r] * ad[1]
            + acc[rt][2][r] * ad[2] + acc[rt][3][r] * ad[3];
    }
    #pragma unroll
    for (int msk = 1; msk < 16; msk <<= 1){
      #pragma unroll
      for (int r = 0; r < 4; ++r){
        ps[r] += __shfl_xor(ps[r], msk, 64);
        pd[r] += __shfl_xor(pd[r], msk, 64);
      }
    }
    if (l15 == 0){
      #pragma unroll
      for (int r = 0; r < 4; ++r){
        int n = m0 + rt * 16 + quad * 4 + r;
        a_src[n * HEADS + w] = ps[r];
        a_dst[n * HEADS + w] = pd[r];
      }
    }
  }
}

// ---- exclusive scan over deg, phase 1 ----
__global__ __launch_bounds__(256) void k_scan1(const int* __restrict__ deg,
                                               int* __restrict__ out,
                                               int* __restrict__ bsum, int N){
  __shared__ int tsum[256];
  int t = threadIdx.x;
  int base = blockIdx.x * 1024 + t * 4;
  int v[4]; int s = 0;
  #pragma unroll
  for (int k = 0; k < 4; ++k){ int i = base + k; v[k] = (i < N) ? deg[i] : 0; s += v[k]; }
  tsum[t] = s;
  __syncthreads();
  for (int off = 1; off < 256; off <<= 1){
    int x = (t >= off) ? tsum[t - off] : 0;
    __syncthreads();
    tsum[t] += x;
    __syncthreads();
  }
  int excl = tsum[t] - s;
  if (t == 255) bsum[blockIdx.x] = tsum[255];
  int run = excl;
  #pragma unroll
  for (int k = 0; k < 4; ++k){ int i = base + k; if (i < N) out[i] = run; run += v[k]; }
}

// ---- phase 2+3 merged ----
__global__ __launch_bounds__(256) void k_scan23(int* __restrict__ rowstart,
                                                const int* __restrict__ bsum,
                                                int N, int E){
  int lane = threadIdx.x & 63;
  int partial = 0;
  for (int i = lane; i < blockIdx.x; i += 64) partial += bsum[i];
  #pragma unroll
  for (int msk = 32; msk; msk >>= 1) partial += __shfl_xor(partial, msk, 64);
  int base = blockIdx.x * 1024 + threadIdx.x * 4;
  #pragma unroll
  for (int k = 0; k < 4; ++k){ int i = base + k; if (i < N) rowstart[i] += partial; }
  if (blockIdx.x == 0 && threadIdx.x == 0) rowstart[N] = E;
}

// ---- scatter (atomic-free) ----
__global__ void k_scatter(const int* __restrict__ srcc, const int* __restrict__ dstc,
                          const int* __restrict__ pos, const int* __restrict__ rowstart,
                          int* __restrict__ csr, int E){
  int e = blockIdx.x * 256 + threadIdx.x;
  if (e < E){
    int d = dstc[e];
    csr[rowstart[d] + pos[e]] = srcc[e];
  }
}

// ---- softmax coefficients: wave = node, all heads; writes coef[h][E] + selfc[n][4] ----
__global__ __launch_bounds__(256) void k_coef(const float* __restrict__ a_src,
    const float* __restrict__ a_dst, const int* __restrict__ rowstart,
    const int* __restrict__ csr, float* __restrict__ coefc /*[H][E]*/,
    float* __restrict__ selfc /*[N][H]*/, int N, int E){
  int w = threadIdx.x >> 6, lane = threadIdx.x & 63;
  int n = blockIdx.x * 4 + w;
  if (n >= N) return;
  int r0 = rowstart[n], r1 = rowstart[n + 1];
  int deg = r1 - r0;
  int total = deg + 1;
  float4 ad4 = *(const float4*)&a_dst[n * HEADS];

  if (total <= 64){
    int jv = n;
    if (lane < deg) jv = csr[r0 + lane];
    float l0 = -1e30f, l1 = -1e30f, l2 = -1e30f, l3 = -1e30f;
    if (lane < total){
      float4 a4 = *(const float4*)&a_src[jv * HEADS];
      l0 = a4.x + ad4.x; l0 = (l0 > 0.f) ? l0 : NEG * l0;
      l1 = a4.y + ad4.y; l1 = (l1 > 0.f) ? l1 : NEG * l1;
      l2 = a4.z + ad4.z; l2 = (l2 > 0.f) ? l2 : NEG * l2;
      l3 = a4.w + ad4.w; l3 = (l3 > 0.f) ? l3 : NEG * l3;
    }
    float p0 = __expf(l0), p1 = __expf(l1), p2 = __expf(l2), p3 = __expf(l3);
    float s0 = p0, s1 = p1, s2 = p2, s3 = p3;
    #pragma unroll
    for (int msk = 32; msk; msk >>= 1){
      s0 += __shfl_xor(s0, msk, 64);
      s1 += __shfl_xor(s1, msk, 64);
      s2 += __shfl_xor(s2, msk, 64);
      s3 += __shfl_xor(s3, msk, 64);
    }
    if (lane < deg){
      coefc[0 * (size_t)E + r0 + lane] = p0 / s0;
      coefc[1 * (size_t)E + r0 + lane] = p1 / s1;
      coefc[2 * (size_t)E + r0 + lane] = p2 / s2;
      coefc[3 * (size_t)E + r0 + lane] = p3 / s3;
    } else if (lane == deg){
      f32x4 sv; sv[0] = p0 / s0; sv[1] = p1 / s1; sv[2] = p2 / s2; sv[3] = p3 / s3;
      *(f32x4*)&selfc[n * HEADS] = sv;
    }
  } else {
    float m[4] = {-1e30f, -1e30f, -1e30f, -1e30f};
    float s[4] = {0.f, 0.f, 0.f, 0.f};
    float adArr[4] = {ad4.x, ad4.y, ad4.z, ad4.w};
    for (int e = lane; e < total; e += 64){
      int j = (e < deg) ? csr[r0 + e] : n;
      float4 a4 = *(const float4*)&a_src[j * HEADS];
      float aa[4] = {a4.x, a4.y, a4.z, a4.w};
      #pragma unroll
      for (int hh = 0; hh < 4; ++hh){
        float l = aa[hh] + adArr[hh];
        l = (l > 0.f) ? l : NEG * l;
        if (l > m[hh]){ s[hh] = s[hh] * __expf(m[hh] - l) + 1.f; m[hh] = l; }
        else            s[hh] += __expf(l - m[hh]);
      }
    }
    #pragma unroll
    for (int hh = 0; hh < 4; ++hh){
      float mm = m[hh], ss = s[hh];
      #pragma unroll
      for (int msk = 32; msk; msk >>= 1){
        float m2 = __shfl_xor(mm, msk, 64);
        float s2 = __shfl_xor(ss, msk, 64);
        float M = fmaxf(mm, m2);
        float ns = 0.f;
        if (mm > -1e29f) ns += ss * __expf(mm - M);
        if (m2 > -1e29f) ns += s2 * __expf(m2 - M);
        mm = M; ss = ns;
      }
      m[hh] = mm; s[hh] = ss;
    }
    float inv[4] = {1.f / s[0], 1.f / s[1], 1.f / s[2], 1.f / s[3]};
    for (int e = lane; e < total; e += 64){
      int j = (e < deg) ? csr[r0 + e] : n;
      float4 a4 = *(const float4*)&a_src[j * HEADS];
      float aa[4] = {a4.x, a4.y, a4.z, a4.w};
      #pragma unroll
      for (int hh = 0; hh < 4; ++hh){
        float l = aa[hh] + adArr[hh];
        l = (l > 0.f) ? l : NEG * l;
        float c = __expf(l - m[hh]) * inv[hh];
        if (e < deg) coefc[(size_t)hh * E + r0 + e] = c;
        else         selfc[n * HEADS + hh] = c;
      }
    }
  }
}

// ---- weighted gather, one head per pass (gridDim.y = HEADS) ----
// Per-head XPh slice = N*64*2B = 3.2 MB -> resident in a 4 MiB XCD L2.
// Wave = (node, head); quarter-wave (16 lanes x 8 B) = one 128-B row; 4 edges/instr.
__global__ __launch_bounds__(256) void k_gather(const unsigned short* __restrict__ XPh,
    const float* __restrict__ coefc, const float* __restrict__ selfc,
    const int* __restrict__ rowstart, const int* __restrict__ csr,
    const float* __restrict__ bias, float* __restrict__ out, int N, int E){
  int w = threadIdx.x >> 6, lane = threadIdx.x & 63;
  int h = blockIdx.y;
  int n = blockIdx.x * 4 + w;
  if (n >= N) return;
  int q = lane >> 4, l16 = lane & 15;
  int r0 = rowstart[n], deg = rowstart[n + 1] - r0;
  int total = deg + 1;
  const unsigned short* xh = XPh + (size_t)h * N * OUTC + l16 * 4;
  const float* ch = coefc + (size_t)h * E + r0;
  float cself = selfc[n * HEADS + h];

  float a0 = 0.f, a1 = 0.f, a2 = 0.f, a3 = 0.f;
  for (int e0 = 0; e0 < total; e0 += 4){
    int e = e0 + q;
    bool v = (e < total);
    int ec = v ? e : 0;
    bool isedge = (ec < deg);
    int j = isedge ? __builtin_nontemporal_load(&csr[r0 + ec]) : n;
    float c = 0.f;
    if (v) c = isedge ? __builtin_nontemporal_load(&ch[ec]) : cself;
    uint2 xv = *(const uint2*)(xh + (size_t)j * OUTC);
    a0 += c * bflo(xv.x); a1 += c * bfhi(xv.x);
    a2 += c * bflo(xv.y); a3 += c * bfhi(xv.y);
  }
  // combine the 4 quarter-wave edge groups
  a0 += __shfl_xor(a0, 16, 64); a0 += __shfl_xor(a0, 32, 64);
  a1 += __shfl_xor(a1, 16, 64); a1 += __shfl_xor(a1, 32, 64);
  a2 += __shfl_xor(a2, 16, 64); a2 += __shfl_xor(a2, 32, 64);
  a3 += __shfl_xor(a3, 16, 64); a3 += __shfl_xor(a3, 32, 64);

  if (q == 0){
    float4 b4 = *(const float4*)&bias[h * OUTC + l16 * 4];
    f32x4 r;
    r[0] = a0 + b4.x; r[1] = a1 + b4.y; r[2] = a2 + b4.z; r[3] = a3 + b4.w;
    __builtin_nontemporal_store(r, (f32x4*)&out[(size_t)n * HC + h * OUTC + l16 * 4]);
  }
}

extern "C" void kernel_launch(void* const* d_in, const int* in_sizes, int n_in,
                              void* d_out, int out_size, void* d_ws, size_t ws_size,
                              hipStream_t stream){
  const float* x       = (const float*)d_in[0];
  const float* W       = (const float*)d_in[1];
  const float* att_src = (const float*)d_in[2];
  const float* att_dst = (const float*)d_in[3];
  const float* bias    = (const float*)d_in[4];
  const int*   ei      = (const int*)d_in[5];
  int N = in_sizes[0] / INC;     // 50000
  int E = in_sizes[5] / 2;       // 800000

  char* p = (char*)d_ws;
  auto alloc = [&](size_t bytes)->char*{
    char* r = p; p += (bytes + 255) & ~(size_t)255; return r;
  };
  unsigned short* Wthi = (unsigned short*)alloc((size_t)INC * HC * 2);
  unsigned short* Wtlo = (unsigned short*)alloc((size_t)INC * HC * 2);
  unsigned short* XPh  = (unsigned short*)alloc((size_t)N * HC * 2);   // head-major [H][N][64]
  float* aSrc          = (float*)alloc((size_t)N * HEADS * 4);
  float* aDst          = (float*)alloc((size_t)N * HEADS * 4);
  int* deg             = (int*)alloc((size_t)N * 4);
  int* rowstart        = (int*)alloc(((size_t)N + 1) * 4);
  int* csr             = (int*)alloc((size_t)E * 4);
  // coefc [H][E] f32 aliases the edge-temp arrays (srcc/dstc/pos dead after k_scatter)
  float* coefc         = (float*)alloc((size_t)HEADS * E * 4);
  int* srcc            = (int*)coefc;
  int* dstc            = srcc + E;
  int* pos             = dstc + E;
  float* selfc         = (float*)alloc((size_t)N * HEADS * 4);
  int* bsum            = (int*)alloc(256 * 4);

  hipMemsetAsync(deg, 0, (size_t)N * 4, stream);
  k_conv_e_hist<<<(E + 255) / 256, 256, 0, stream>>>(ei, srcc, dstc, pos, deg, E);

  k_split_w<<<(INC * HC) / 256, 256, 0, stream>>>(W, Wthi, Wtlo);
  k_gemm_fused<<<(N + 63) / 64, 256, 0, stream>>>(x, Wthi, Wtlo, att_src, att_dst,
                                                  XPh, aSrc, aDst, N);

  int nb = (N + 1023) / 1024;
  k_scan1<<<nb, 256, 0, stream>>>(deg, rowstart, bsum, N);
  k_scan23<<<nb, 256, 0, stream>>>(rowstart, bsum, N, E);
  k_scatter<<<(E + 255) / 256, 256, 0, stream>>>(srcc, dstc, pos, rowstart, csr, E);

  k_coef<<<(N + 3) / 4, 256, 0, stream>>>(aSrc, aDst, rowstart, csr, coefc, selfc, N, E);

  dim3 ggrid((N + 3) / 4, HEADS);
  k_gather<<<ggrid, 256, 0, stream>>>(XPh, coefc, selfc, rowstart, csr, bias,
                                      (float*)d_out, N, E);
}

// Round 4
// 238.138 us; speedup vs baseline: 1.5303x; 1.5303x over previous
//
#include <hip/hip_runtime.h>

#define HEADS 4
#define OUTC 64
#define INC 128
#define HC 256   // HEADS*OUTC
#define NEG 0.2f

typedef __attribute__((ext_vector_type(8))) short bf16x8;
typedef __attribute__((ext_vector_type(4))) float f32x4;

static __device__ __forceinline__ float bf2f(unsigned short u){
  unsigned int x = ((unsigned int)u) << 16;
  return __uint_as_float(x);
}
static __device__ __forceinline__ unsigned short f2bf(float f){
  unsigned int x = __float_as_uint(f);
  unsigned int lsb = (x >> 16) & 1u;
  x += 0x7fffu + lsb;           // RNE
  return (unsigned short)(x >> 16);
}
static __device__ __forceinline__ void split8(float4 a, float4 b, bf16x8& hi, bf16x8& lo){
  float v[8] = {a.x, a.y, a.z, a.w, b.x, b.y, b.z, b.w};
  #pragma unroll
  for (int i = 0; i < 8; ++i){
    unsigned short h = f2bf(v[i]);
    hi[i] = (short)h;
    lo[i] = (short)f2bf(v[i] - bf2f(h));
  }
}

#define SPLITB 128   // (INC*HC)/256 blocks for W-split

// ---- merged: W split+transpose (blocks 0..127) | edge canonicalize + degree hist ----
__global__ void k_pre(const float* __restrict__ W, unsigned short* __restrict__ Wthi,
                      unsigned short* __restrict__ Wtlo, const int* __restrict__ ei,
                      int* __restrict__ srcc, int* __restrict__ dstc,
                      int* __restrict__ pos, int* __restrict__ deg, int E){
  if (blockIdx.x < SPLITB){
    int t = blockIdx.x * 256 + threadIdx.x;      // 0..32767
    int k = t >> 8, n = t & 255;
    float v = W[t];
    unsigned short hi = f2bf(v);
    Wthi[n * INC + k] = hi;
    Wtlo[n * INC + k] = f2bf(v - bf2f(hi));
    return;
  }
  int e = (blockIdx.x - SPLITB) * 256 + threadIdx.x;
  bool valid = (e < E);
  int ee = valid ? e : 0;
  int hiw = ei[2 * ee + 1];
  bool hz = valid ? (hiw == 0) : true;
  unsigned long long mask = __ballot(hz);
  bool i64 = (mask == ~0ULL);
  int s, d;
  if (i64){ s = ei[2 * ee]; d = ei[2 * (size_t)E + 2 * ee]; }
  else    { s = ei[ee];     d = ei[(size_t)E + ee]; }
  if (valid){
    srcc[e] = s; dstc[e] = d;
    pos[e] = atomicAdd(&deg[d], 1);
  }
}

// ---- fused GEMM + attention logits: block = 64 rows x 256 cols ----
// Wave w = head w (cols w*64..w*64+63) for all 64 rows. NEW: each wave loads+splits
// ONLY its own 16 X rows into LDS; all waves read all 64 rows' fragments from LDS.
// Cuts split8 VALU and X global traffic 4x vs round-0.
__global__ __launch_bounds__(256) void k_gemm_fused(const float* __restrict__ X,
    const unsigned short* __restrict__ Wthi, const unsigned short* __restrict__ Wtlo,
    const float* __restrict__ att_src, const float* __restrict__ att_dst,
    unsigned short* __restrict__ XPh, float* __restrict__ a_src, float* __restrict__ a_dst,
    int N){
  __shared__ unsigned short shi[64][40];         // 32 cols padded to 40 (>=2-way only)
  __shared__ unsigned short slo[64][40];
  int w = threadIdx.x >> 6, lane = threadIdx.x & 63;
  int m0 = blockIdx.x * 64;
  int quad = lane >> 4;
  int l15 = lane & 15;
  int colg[4];
  #pragma unroll
  for (int t = 0; t < 4; ++t) colg[t] = w * 64 + t * 16 + l15;

  bool rv[4];
  #pragma unroll
  for (int rt = 0; rt < 4; ++rt) rv[rt] = (m0 + rt * 16) < N;  // N%16==0
  int myrow = rv[w] ? (m0 + w * 16 + l15) : 0;   // the 16 rows THIS wave stages

  f32x4 acc[4][4];                               // [rt][t]
  #pragma unroll
  for (int rt = 0; rt < 4; ++rt)
    #pragma unroll
    for (int t = 0; t < 4; ++t) acc[rt][t] = (f32x4){0.f, 0.f, 0.f, 0.f};

  #pragma unroll
  for (int kk = 0; kk < 4; ++kk){
    const float* xr = X + (size_t)myrow * INC + kk * 32 + quad * 8;
    float4 va = *(const float4*)xr;
    float4 vb = *(const float4*)(xr + 4);
    // W fragments for this k-step (independent of LDS traffic)
    bf16x8 bh[4], bl[4];
    #pragma unroll
    for (int t = 0; t < 4; ++t){
      size_t bo = (size_t)colg[t] * INC + kk * 32 + quad * 8;
      bh[t] = *(const bf16x8*)(Wthi + bo);
      bl[t] = *(const bf16x8*)(Wtlo + bo);
    }
    bf16x8 ah1, al1;
    split8(va, vb, ah1, al1);                    // ONE split per wave per kk (was 4)
    if (kk) __syncthreads();                     // protect LDS from previous k-step reads
    *(bf16x8*)&shi[w * 16 + l15][quad * 8] = ah1;
    *(bf16x8*)&slo[w * 16 + l15][quad * 8] = al1;
    __syncthreads();
    bf16x8 ah[4], al[4];
    #pragma unroll
    for (int rt = 0; rt < 4; ++rt){
      ah[rt] = *(const bf16x8*)&shi[rt * 16 + l15][quad * 8];
      al[rt] = *(const bf16x8*)&slo[rt * 16 + l15][quad * 8];
    }
    #pragma unroll
    for (int rt = 0; rt < 4; ++rt){
      #pragma unroll
      for (int t = 0; t < 4; ++t){
        acc[rt][t] = __builtin_amdgcn_mfma_f32_16x16x32_bf16(ah[rt], bh[t], acc[rt][t], 0, 0, 0);
        acc[rt][t] = __builtin_amdgcn_mfma_f32_16x16x32_bf16(ah[rt], bl[t], acc[rt][t], 0, 0, 0);
        acc[rt][t] = __builtin_amdgcn_mfma_f32_16x16x32_bf16(al[rt], bh[t], acc[rt][t], 0, 0, 0);
      }
    }
  }

  // store XPh (bf16). C/D layout: col=l15, row=quad*4+r
  #pragma unroll
  for (int rt = 0; rt < 4; ++rt){
    if (!rv[rt]) continue;
    #pragma unroll
    for (int t = 0; t < 4; ++t){
      #pragma unroll
      for (int r = 0; r < 4; ++r){
        XPh[(size_t)(m0 + rt * 16 + quad * 4 + r) * HC + colg[t]] = f2bf(acc[rt][t][r]);
      }
    }
  }

  // epilogue: head-w logits for the 64 rows
  float as[4], ad[4];
  #pragma unroll
  for (int t = 0; t < 4; ++t){
    as[t] = att_src[colg[t]];
    ad[t] = att_dst[colg[t]];
  }
  #pragma unroll
  for (int rt = 0; rt < 4; ++rt){
    if (!rv[rt]) continue;
    float ps[4], pd[4];
    #pragma unroll
    for (int r = 0; r < 4; ++r){
      ps[r] = acc[rt][0][r] * as[0] + acc[rt][1][r] * as[1]
            + acc[rt][2][r] * as[2] + acc[rt][3][r] * as[3];
      pd[r] = acc[rt][0][r] * ad[0] + acc[rt][1][r] * ad[1]
            + acc[rt][2][r] * ad[2] + acc[rt][3][r] * ad[3];
    }
    #pragma unroll
    for (int msk = 1; msk < 16; msk <<= 1){
      #pragma unroll
      for (int r = 0; r < 4; ++r){
        ps[r] += __shfl_xor(ps[r], msk, 64);
        pd[r] += __shfl_xor(pd[r], msk, 64);
      }
    }
    if (l15 == 0){
      #pragma unroll
      for (int r = 0; r < 4; ++r){
        int n = m0 + rt * 16 + quad * 4 + r;
        a_src[n * HEADS + w] = ps[r];
        a_dst[n * HEADS + w] = pd[r];
      }
    }
  }
}

// ---- exclusive scan over deg, phase 1 ----
__global__ __launch_bounds__(256) void k_scan1(const int* __restrict__ deg,
                                               int* __restrict__ out,
                                               int* __restrict__ bsum, int N){
  __shared__ int tsum[256];
  int t = threadIdx.x;
  int base = blockIdx.x * 1024 + t * 4;
  int v[4]; int s = 0;
  #pragma unroll
  for (int k = 0; k < 4; ++k){ int i = base + k; v[k] = (i < N) ? deg[i] : 0; s += v[k]; }
  tsum[t] = s;
  __syncthreads();
  for (int off = 1; off < 256; off <<= 1){
    int x = (t >= off) ? tsum[t - off] : 0;
    __syncthreads();
    tsum[t] += x;
    __syncthreads();
  }
  int excl = tsum[t] - s;
  if (t == 255) bsum[blockIdx.x] = tsum[255];
  int run = excl;
  #pragma unroll
  for (int k = 0; k < 4; ++k){ int i = base + k; if (i < N) out[i] = run; run += v[k]; }
}

// ---- phase 2+3 merged ----
__global__ __launch_bounds__(256) void k_scan23(int* __restrict__ rowstart,
                                                const int* __restrict__ bsum,
                                                int N, int E){
  int lane = threadIdx.x & 63;
  int partial = 0;
  for (int i = lane; i < blockIdx.x; i += 64) partial += bsum[i];
  #pragma unroll
  for (int msk = 32; msk; msk >>= 1) partial += __shfl_xor(partial, msk, 64);
  int base = blockIdx.x * 1024 + threadIdx.x * 4;
  #pragma unroll
  for (int k = 0; k < 4; ++k){ int i = base + k; if (i < N) rowstart[i] += partial; }
  if (blockIdx.x == 0 && threadIdx.x == 0) rowstart[N] = E;
}

// ---- scatter (atomic-free) ----
__global__ void k_scatter(const int* __restrict__ srcc, const int* __restrict__ dstc,
                          const int* __restrict__ pos, const int* __restrict__ rowstart,
                          int* __restrict__ csr, int E){
  int e = blockIdx.x * 256 + threadIdx.x;
  if (e < E){
    int d = dstc[e];
    csr[rowstart[d] + pos[e]] = srcc[e];
  }
}

// ---- fused softmax-coef + gather: wave = node (all 4 heads) ----
// Round-0 structure (8 row-gathers in flight, full 512-B row per edge).
// All LDS use is wave-local -> no __syncthreads needed.
__global__ __launch_bounds__(256) void k_fused(const unsigned short* __restrict__ XPh,
    const float* __restrict__ a_src, const float* __restrict__ a_dst,
    const int* __restrict__ rowstart, const int* __restrict__ csr,
    const float* __restrict__ bias, float* __restrict__ out, int N){
  __shared__ float sh[4][64][4];               // [wave][slot][head]
  int w = threadIdx.x >> 6, lane = threadIdx.x & 63;
  int n = blockIdx.x * 4 + w;
  bool alive = (n < N);
  if (!alive) n = 0;
  int r0 = rowstart[n], r1 = rowstart[n + 1];
  int deg = r1 - r0;
  int total = deg + 1;
  int h = lane >> 4;
  float4 ad4 = *(const float4*)&a_dst[n * HEADS];
  bool fast = (total <= 64);
  int jv = n;
  float msel = 0.f, inv_sel = 0.f;

  if (fast){
    if (lane < deg) jv = csr[r0 + lane];
    float l0 = -1e30f, l1 = -1e30f, l2 = -1e30f, l3 = -1e30f;
    if (lane < total){
      float4 a4 = *(const float4*)&a_src[jv * HEADS];
      l0 = a4.x + ad4.x; l0 = (l0 > 0.f) ? l0 : NEG * l0;
      l1 = a4.y + ad4.y; l1 = (l1 > 0.f) ? l1 : NEG * l1;
      l2 = a4.z + ad4.z; l2 = (l2 > 0.f) ? l2 : NEG * l2;
      l3 = a4.w + ad4.w; l3 = (l3 > 0.f) ? l3 : NEG * l3;
    }
    float p0 = __expf(l0), p1 = __expf(l1), p2 = __expf(l2), p3 = __expf(l3);
    float s0 = p0, s1 = p1, s2 = p2, s3 = p3;
    #pragma unroll
    for (int msk = 32; msk; msk >>= 1){
      s0 += __shfl_xor(s0, msk, 64);
      s1 += __shfl_xor(s1, msk, 64);
      s2 += __shfl_xor(s2, msk, 64);
      s3 += __shfl_xor(s3, msk, 64);
    }
    if (lane < total){
      sh[w][lane][0] = p0 / s0;
      sh[w][lane][1] = p1 / s1;
      sh[w][lane][2] = p2 / s2;
      sh[w][lane][3] = p3 / s3;
    }
  } else {
    float m[4] = {-1e30f, -1e30f, -1e30f, -1e30f};
    float s[4] = {0.f, 0.f, 0.f, 0.f};
    float adArr[4] = {ad4.x, ad4.y, ad4.z, ad4.w};
    for (int e = lane; e < total; e += 64){
      int j = (e < deg) ? csr[r0 + e] : n;
      float4 a4 = *(const float4*)&a_src[j * HEADS];
      float aa[4] = {a4.x, a4.y, a4.z, a4.w};
      #pragma unroll
      for (int hh = 0; hh < 4; ++hh){
        float l = aa[hh] + adArr[hh];
        l = (l > 0.f) ? l : NEG * l;
        if (l > m[hh]){ s[hh] = s[hh] * __expf(m[hh] - l) + 1.f; m[hh] = l; }
        else            s[hh] += __expf(l - m[hh]);
      }
    }
    #pragma unroll
    for (int hh = 0; hh < 4; ++hh){
      float mm = m[hh], ss = s[hh];
      #pragma unroll
      for (int msk = 32; msk; msk >>= 1){
        float m2 = __shfl_xor(mm, msk, 64);
        float s2 = __shfl_xor(ss, msk, 64);
        float M = fmaxf(mm, m2);
        float ns = 0.f;
        if (mm > -1e29f) ns += ss * __expf(mm - M);
        if (m2 > -1e29f) ns += s2 * __expf(m2 - M);
        mm = M; ss = ns;
      }
      m[hh] = mm; s[hh] = ss;
    }
    msel    = (h == 0) ? m[0] : (h == 1) ? m[1] : (h == 2) ? m[2] : m[3];
    inv_sel = 1.f / ((h == 0) ? s[0] : (h == 1) ? s[1] : (h == 2) ? s[2] : s[3]);
  }

  float a0 = 0.f, a1 = 0.f, a2 = 0.f, a3 = 0.f;
  const unsigned short* xb = XPh + lane * 4;
  if (fast){
    int e = 0;
    for (; e + 8 <= total; e += 8){
      int jj[8]; float cf[8]; ushort4 xv[8];
      #pragma unroll
      for (int q = 0; q < 8; ++q){
        jj[q] = __builtin_amdgcn_readlane(jv, e + q);
        cf[q] = sh[w][e + q][h];
      }
      #pragma unroll
      for (int q = 0; q < 8; ++q) xv[q] = *(const ushort4*)(xb + (size_t)jj[q] * HC);
      #pragma unroll
      for (int q = 0; q < 8; ++q){
        a0 += cf[q] * bf2f(xv[q].x); a1 += cf[q] * bf2f(xv[q].y);
        a2 += cf[q] * bf2f(xv[q].z); a3 += cf[q] * bf2f(xv[q].w);
      }
    }
    for (; e < total; ++e){
      int j = __builtin_amdgcn_readlane(jv, e);
      float c = sh[w][e][h];
      ushort4 xv = *(const ushort4*)(xb + (size_t)j * HC);
      a0 += c * bf2f(xv.x); a1 += c * bf2f(xv.y); a2 += c * bf2f(xv.z); a3 += c * bf2f(xv.w);
    }
  } else {
    float adh = (h == 0) ? ad4.x : (h == 1) ? ad4.y : (h == 2) ? ad4.z : ad4.w;
    for (int e = 0; e < total; ++e){
      int j = (e < deg) ? csr[r0 + e] : n;
      float4 a4 = *(const float4*)&a_src[j * HEADS];
      float ah = (h == 0) ? a4.x : (h == 1) ? a4.y : (h == 2) ? a4.z : a4.w;
      float l = ah + adh;
      l = (l > 0.f) ? l : NEG * l;
      float c = __expf(l - msel) * inv_sel;
      ushort4 xv = *(const ushort4*)(xb + (size_t)j * HC);
      a0 += c * bf2f(xv.x); a1 += c * bf2f(xv.y); a2 += c * bf2f(xv.z); a3 += c * bf2f(xv.w);
    }
  }
  if (alive){
    float4 b4 = *(const float4*)&bias[lane * 4];
    f32x4 r;
    r[0] = a0 + b4.x; r[1] = a1 + b4.y; r[2] = a2 + b4.z; r[3] = a3 + b4.w;
    __builtin_nontemporal_store(r, (f32x4*)&out[(size_t)n * HC + lane * 4]);
  }
}

extern "C" void kernel_launch(void* const* d_in, const int* in_sizes, int n_in,
                              void* d_out, int out_size, void* d_ws, size_t ws_size,
                              hipStream_t stream){
  const float* x       = (const float*)d_in[0];
  const float* W       = (const float*)d_in[1];
  const float* att_src = (const float*)d_in[2];
  const float* att_dst = (const float*)d_in[3];
  const float* bias    = (const float*)d_in[4];
  const int*   ei      = (const int*)d_in[5];
  int N = in_sizes[0] / INC;     // 50000
  int E = in_sizes[5] / 2;       // 800000

  char* p = (char*)d_ws;
  auto alloc = [&](size_t bytes)->char*{
    char* r = p; p += (bytes + 255) & ~(size_t)255; return r;
  };
  unsigned short* Wthi = (unsigned short*)alloc((size_t)INC * HC * 2);
  unsigned short* Wtlo = (unsigned short*)alloc((size_t)INC * HC * 2);
  unsigned short* XPh  = (unsigned short*)alloc((size_t)N * HC * 2);
  float* aSrc          = (float*)alloc((size_t)N * HEADS * 4);
  float* aDst          = (float*)alloc((size_t)N * HEADS * 4);
  int* deg             = (int*)alloc((size_t)N * 4);
  int* rowstart        = (int*)alloc(((size_t)N + 1) * 4);
  int* srcc            = (int*)alloc((size_t)E * 4);
  int* dstc            = (int*)alloc((size_t)E * 4);
  int* pos             = (int*)alloc((size_t)E * 4);
  int* csr             = (int*)alloc((size_t)E * 4);
  int* bsum            = (int*)alloc(256 * 4);

  hipMemsetAsync(deg, 0, (size_t)N * 4, stream);
  k_pre<<<SPLITB + (E + 255) / 256, 256, 0, stream>>>(W, Wthi, Wtlo, ei,
                                                      srcc, dstc, pos, deg, E);
  k_gemm_fused<<<(N + 63) / 64, 256, 0, stream>>>(x, Wthi, Wtlo, att_src, att_dst,
                                                  XPh, aSrc, aDst, N);

  int nb = (N + 1023) / 1024;
  k_scan1<<<nb, 256, 0, stream>>>(deg, rowstart, bsum, N);
  k_scan23<<<nb, 256, 0, stream>>>(rowstart, bsum, N, E);
  k_scatter<<<(E + 255) / 256, 256, 0, stream>>>(srcc, dstc, pos, rowstart, csr, E);

  k_fused<<<(N + 3) / 4, 256, 0, stream>>>(XPh, aSrc, aDst, rowstart, csr, bias,
                                           (float*)d_out, N);
}